// Round 1
// baseline (428.977 us; speedup 1.0000x reference)
//
#include <hip/hip_runtime.h>
#include <hip/hip_bf16.h>
#include <math.h>

#define L_    4096
#define C96   96
#define DI_   192
#define Nn    16
#define Rr    6
#define Kk    4
#define HW_   64
#define HF_   255
#define CH_   128
#define NCH_  32

__device__ __forceinline__ float sp_softplus(float s) {
    return fmaxf(s, 0.f) + log1pf(expf(-fabsf(s)));
}
__device__ __forceinline__ float sp_silu(float s) {
    return s / (1.f + expf(-s));
}

// K1: RMS-LN over C=96 channels (per spatial position). n1 layout (c, l).
__global__ void k_rmsln1(const float* __restrict__ x, const float* __restrict__ w,
                         const float* __restrict__ b, float* __restrict__ n1) {
    int l = blockIdx.x * blockDim.x + threadIdx.x;
    if (l >= L_) return;
    float ss = 0.f;
    for (int c = 0; c < C96; ++c) { float v = x[c * L_ + l]; ss += v * v; }
    float r = rsqrtf(ss * (1.f / C96) + 1e-6f);
    for (int c = 0; c < C96; ++c)
        n1[c * L_ + l] = x[c * L_ + l] * r * w[c] + b[c];
}

// K2: in_proj GEMM: xzT[o, l] = sum_c n1[c,l] * W[o,c].  O=384. 8-way o blocking.
__global__ void k_inproj(const float* __restrict__ n1, const float* __restrict__ W,
                         float* __restrict__ xzT) {
    int l = blockIdx.x * 64 + threadIdx.x;
    int o0 = (blockIdx.y * 4 + threadIdx.y) * 8;
    float acc[8] = {0.f, 0.f, 0.f, 0.f, 0.f, 0.f, 0.f, 0.f};
    for (int c = 0; c < C96; ++c) {
        float v = n1[c * L_ + l];
#pragma unroll
        for (int j = 0; j < 8; ++j) acc[j] += v * W[(o0 + j) * C96 + c];
    }
#pragma unroll
    for (int j = 0; j < 8; ++j) xzT[(o0 + j) * L_ + l] = acc[j];
}

// K3: depthwise 3x3 conv (SAME) + bias + SiLU on xc (192, 64, 64). Input = xzT rows 0..191.
__global__ void k_conv192(const float* __restrict__ xc, const float* __restrict__ w,
                          const float* __restrict__ b, float* __restrict__ out) {
    int idx = blockIdx.x * 256 + threadIdx.x;
    if (idx >= DI_ * L_) return;
    int c = idx / L_, l = idx % L_;
    int h = l >> 6, wc = l & 63;
    float s = b[c];
#pragma unroll
    for (int di = -1; di <= 1; ++di)
#pragma unroll
        for (int dj = -1; dj <= 1; ++dj) {
            int hh = h + di, ww = wc + dj;
            if (hh >= 0 && hh < HW_ && ww >= 0 && ww < HW_)
                s += xc[c * L_ + hh * HW_ + ww] * w[c * 9 + (di + 1) * 3 + (dj + 1)];
        }
    out[idx] = sp_silu(s);
}

// K4: materialize 4 direction views xs[(k*DI+d)*L + l]
__global__ void k_build_xs(const float* __restrict__ xconv, float* __restrict__ xs) {
    int idx = blockIdx.x * 256 + threadIdx.x;
    if (idx >= Kk * DI_ * L_) return;
    int l = idx % L_; int kd = idx / L_; int d = kd % DI_; int k = kd / DI_;
    int ll = (k & 2) ? (L_ - 1 - l) : l;
    int pos = (k & 1) ? ((ll & 63) * 64 + (ll >> 6)) : ll;
    xs[idx] = xconv[d * L_ + pos];
}

// K5: x_dbl[k, c, l] = sum_d xs[k,d,l] * Wxp[k,c,d].  c in 0..37, 8-way c blocking.
__global__ void k_xdbl(const float* __restrict__ xs, const float* __restrict__ Wxp,
                       float* __restrict__ xdbl) {
    int l = blockIdx.x * 64 + threadIdx.x;
    int k = blockIdx.y;
    int c0 = blockIdx.z * 8;
    int ce = min(38 - c0, 8);
    float acc[8] = {0.f, 0.f, 0.f, 0.f, 0.f, 0.f, 0.f, 0.f};
    for (int d = 0; d < DI_; ++d) {
        float v = xs[(k * DI_ + d) * L_ + l];
#pragma unroll
        for (int j = 0; j < 8; ++j)
            if (j < ce) acc[j] += v * Wxp[(k * 38 + c0 + j) * DI_ + d];
    }
#pragma unroll
    for (int j = 0; j < 8; ++j)
        if (j < ce) xdbl[(k * 38 + c0 + j) * L_ + l] = acc[j];
}

// K6: delta[kd, l] = softplus(sum_r dts[k,r,l] * dtw[kd,r] + dtb[kd])
__global__ void k_delta(const float* __restrict__ xdbl, const float* __restrict__ dtw,
                        const float* __restrict__ dtb, float* __restrict__ delta) {
    int idx = blockIdx.x * 256 + threadIdx.x;
    if (idx >= Kk * DI_ * L_) return;
    int l = idx % L_; int kd = idx / L_; int k = kd / DI_;
    float s = dtb[kd];
#pragma unroll
    for (int r = 0; r < Rr; ++r)
        s += xdbl[(k * 38 + r) * L_ + l] * dtw[kd * Rr + r];
    delta[idx] = sp_softplus(s);
}

// K7: transpose Bs, Cs to (k, l, n) layout for coalesced scan loads.
__global__ void k_bct(const float* __restrict__ xdbl, float* __restrict__ BsT,
                      float* __restrict__ CsT) {
    int idx = blockIdx.x * 256 + threadIdx.x;
    if (idx >= Kk * L_ * Nn) return;
    int n = idx & 15; int r = idx >> 4; int l = r % L_; int k = r / L_;
    BsT[idx] = xdbl[(k * 38 + 6 + n) * L_ + l];
    CsT[idx] = xdbl[(k * 38 + 22 + n) * L_ + l];
}

// K8: scan phase 1 — per-chunk (prod a, partial h) with h0 = 0.
// group (16 lanes = n) handles one (kd, chunk). 24576 groups.
__global__ void k_scan1(const float* __restrict__ delta, const float* __restrict__ xs,
                        const float* __restrict__ BsT, const float* __restrict__ A_logs,
                        float* __restrict__ P, float* __restrict__ S) {
    int g = blockIdx.x * 16 + (threadIdx.x >> 4);
    int n = threadIdx.x & 15;
    int chunk = g & 31; int kd = g >> 5; int k = kd / DI_;
    float A = -__expf(A_logs[kd * Nn + n]);
    float h = 0.f, p = 1.f;
    int base = kd * L_ + chunk * CH_;
    int base_b = (k * L_ + chunk * CH_) * Nn + n;
    for (int i = 0; i < CH_; ++i) {
        float dl = delta[base + i];
        float ul = xs[base + i];
        float bv = BsT[base_b + i * Nn];
        float e = __expf(dl * A);
        h = e * h + dl * ul * bv;
        p *= e;
    }
    int o = g * Nn + n;
    P[o] = p; S[o] = h;
}

// K9: scan phase 2 — exclusive prefix over 32 chunks per (kd).
__global__ void k_scan2(const float* __restrict__ P, const float* __restrict__ S,
                        float* __restrict__ HS) {
    int g = blockIdx.x * 16 + (threadIdx.x >> 4);  // kd, 768 total
    int n = threadIdx.x & 15;
    if (g >= Kk * DI_) return;
    float h = 0.f;
    for (int c = 0; c < NCH_; ++c) {
        int o = (g * NCH_ + c) * Nn + n;
        HS[o] = h;
        h = P[o] * h + S[o];
    }
}

// K10: scan phase 3 — replay with correct h0, emit y = sum_n h*C + Dp*u.
__global__ void k_scan3(const float* __restrict__ delta, const float* __restrict__ xs,
                        const float* __restrict__ BsT, const float* __restrict__ CsT,
                        const float* __restrict__ A_logs, const float* __restrict__ Ds,
                        const float* __restrict__ HS, float* __restrict__ scan_y) {
    int g = blockIdx.x * 16 + (threadIdx.x >> 4);
    int n = threadIdx.x & 15;
    int chunk = g & 31; int kd = g >> 5; int k = kd / DI_;
    float A = -__expf(A_logs[kd * Nn + n]);
    float Dp = Ds[kd];
    float h = HS[(kd * NCH_ + chunk) * Nn + n];
    int base = kd * L_ + chunk * CH_;
    int base_bc = (k * L_ + chunk * CH_) * Nn + n;
    for (int i = 0; i < CH_; ++i) {
        float dl = delta[base + i];
        float ul = xs[base + i];
        float bv = BsT[base_bc + i * Nn];
        float cv = CsT[base_bc + i * Nn];
        float e = __expf(dl * A);
        h = e * h + dl * ul * bv;
        float psum = h * cv;
        psum += __shfl_xor(psum, 1, 64);
        psum += __shfl_xor(psum, 2, 64);
        psum += __shfl_xor(psum, 4, 64);
        psum += __shfl_xor(psum, 8, 64);
        if (n == 0) scan_y[base + i] = psum + Dp * ul;
    }
}

// K11: per-position: combine 4 directions + LayerNorm(DI) + silu(z) gate +
//      out_proj + residual + RMSNorm2. Block = 192 threads, 1 block per l.
__global__ __launch_bounds__(192) void k_combine(
        const float* __restrict__ scan_y, const float* __restrict__ onw,
        const float* __restrict__ onb, const float* __restrict__ xzT,
        const float* __restrict__ Wout, const float* __restrict__ x,
        const float* __restrict__ w2, const float* __restrict__ b2,
        float* __restrict__ x2, float* __restrict__ n2) {
    int l = blockIdx.x; int t = threadIdx.x;
    __shared__ float sh[192];
    __shared__ float shy[192];
    int h = l >> 6, wc = l & 63;
    int lT = (wc << 6) | h;
    float y = scan_y[(0 * DI_ + t) * L_ + l]
            + scan_y[(2 * DI_ + t) * L_ + (L_ - 1 - l)]
            + scan_y[(1 * DI_ + t) * L_ + lT]
            + scan_y[(3 * DI_ + t) * L_ + (L_ - 1 - lT)];
    sh[t] = y; __syncthreads();
    if (t < 64) {
        float v = sh[t] + sh[t + 64] + sh[t + 128];
        for (int m = 32; m; m >>= 1) v += __shfl_xor(v, m, 64);
        if (t == 0) sh[0] = v;
    }
    __syncthreads();
    float mu = sh[0] * (1.f / DI_);
    __syncthreads();
    float yc = y - mu;
    sh[t] = yc * yc; __syncthreads();
    if (t < 64) {
        float v = sh[t] + sh[t + 64] + sh[t + 128];
        for (int m = 32; m; m >>= 1) v += __shfl_xor(v, m, 64);
        if (t == 0) sh[0] = v;
    }
    __syncthreads();
    float var = sh[0] * (1.f / DI_);
    float zv = xzT[(DI_ + t) * L_ + l];
    float yn = yc * rsqrtf(var + 1e-5f) * onw[t] + onb[t];
    yn *= sp_silu(zv);
    shy[t] = yn;
    __syncthreads();
    float x2v = 0.f;
    if (t < C96) {
        float acc = 0.f;
        for (int d = 0; d < DI_; ++d) acc += shy[d] * Wout[t * DI_ + d];
        x2v = x[t * L_ + l] + acc;
    }
    __syncthreads();
    sh[t] = (t < C96) ? x2v * x2v : 0.f;
    __syncthreads();
    if (t < 32) {
        float v = sh[t] + sh[t + 32] + sh[t + 64];
        for (int m = 16; m; m >>= 1) v += __shfl_xor(v, m, 64);
        if (t == 0) sh[0] = v;
    }
    __syncthreads();
    float r2 = rsqrtf(sh[0] * (1.f / C96) + 1e-6f);
    if (t < C96) {
        x2[t * L_ + l] = x2v;
        n2[t * L_ + l] = x2v * r2 * w2[t] + b2[t];
    }
}

// K12: EDFFN pin GEMM: hf[o, l] = sum_c n2[c,l] * W[o,c].  O=510, 10-way blocking.
__global__ void k_pin(const float* __restrict__ n2, const float* __restrict__ W,
                      float* __restrict__ hf) {
    int l = blockIdx.x * 64 + threadIdx.x;
    int g = blockIdx.y * 4 + threadIdx.y;
    if (g >= 51) return;
    int o0 = g * 10;
    float acc[10] = {0.f, 0.f, 0.f, 0.f, 0.f, 0.f, 0.f, 0.f, 0.f, 0.f};
    for (int c = 0; c < C96; ++c) {
        float v = n2[c * L_ + l];
#pragma unroll
        for (int j = 0; j < 10; ++j) acc[j] += v * W[(o0 + j) * C96 + c];
    }
#pragma unroll
    for (int j = 0; j < 10; ++j) hf[(o0 + j) * L_ + l] = acc[j];
}

// K13: depthwise 3x3 (no bias) on 510 channels + GELU(h1)*h2 gate. g (255, l).
__global__ void k_ffnconv(const float* __restrict__ hf, const float* __restrict__ w,
                          float* __restrict__ g) {
    int idx = blockIdx.x * 256 + threadIdx.x;
    if (idx >= HF_ * L_) return;
    int c = idx / L_, l = idx % L_;
    int h = l >> 6, wc = l & 63;
    float s1 = 0.f, s2 = 0.f;
#pragma unroll
    for (int di = -1; di <= 1; ++di)
#pragma unroll
        for (int dj = -1; dj <= 1; ++dj) {
            int hh = h + di, ww = wc + dj;
            if (hh >= 0 && hh < HW_ && ww >= 0 && ww < HW_) {
                int p = hh * HW_ + ww;
                int widx = (di + 1) * 3 + (dj + 1);
                s1 += hf[c * L_ + p] * w[c * 9 + widx];
                s2 += hf[(c + HF_) * L_ + p] * w[(c + HF_) * 9 + widx];
            }
        }
    float ge = 0.5f * s1 * (1.f + erff(s1 * 0.70710678118654752f));
    g[idx] = ge * s2;
}

// K14: pout GEMM + final residual: out[c,l] = x2[c,l] + sum_i g[i,l]*W[c,i].
__global__ void k_pout(const float* __restrict__ g, const float* __restrict__ W,
                       const float* __restrict__ x2, float* __restrict__ out) {
    int l = blockIdx.x * 64 + threadIdx.x;
    int c0 = (blockIdx.y * 4 + threadIdx.y) * 8;
    float acc[8] = {0.f, 0.f, 0.f, 0.f, 0.f, 0.f, 0.f, 0.f};
    for (int i = 0; i < HF_; ++i) {
        float v = g[i * L_ + l];
#pragma unroll
        for (int j = 0; j < 8; ++j) acc[j] += v * W[(c0 + j) * HF_ + i];
    }
#pragma unroll
    for (int j = 0; j < 8; ++j)
        out[(c0 + j) * L_ + l] = x2[(c0 + j) * L_ + l] + acc[j];
}

extern "C" void kernel_launch(void* const* d_in, const int* in_sizes, int n_in,
                              void* d_out, int out_size, void* d_ws, size_t ws_size,
                              hipStream_t stream) {
    const float* x         = (const float*)d_in[0];
    const float* norm1_w   = (const float*)d_in[1];
    const float* norm1_b   = (const float*)d_in[2];
    const float* in_proj_w = (const float*)d_in[3];
    const float* conv2d_w  = (const float*)d_in[4];
    const float* conv2d_b  = (const float*)d_in[5];
    const float* x_proj_w  = (const float*)d_in[6];
    const float* dt_projs_w= (const float*)d_in[7];
    const float* dt_projs_b= (const float*)d_in[8];
    const float* A_logs    = (const float*)d_in[9];
    const float* Ds        = (const float*)d_in[10];
    const float* out_norm_w= (const float*)d_in[11];
    const float* out_norm_b= (const float*)d_in[12];
    const float* out_proj_w= (const float*)d_in[13];
    const float* norm2_w   = (const float*)d_in[14];
    const float* norm2_b   = (const float*)d_in[15];
    const float* pin_w     = (const float*)d_in[16];
    const float* dw_w      = (const float*)d_in[17];
    const float* pout_w    = (const float*)d_in[18];

    float* ws = (float*)d_ws;
    float* n1     = ws; ws += C96 * L_;
    float* xzT    = ws; ws += 2 * DI_ * L_;
    float* xconv  = ws; ws += DI_ * L_;
    float* xs     = ws; ws += Kk * DI_ * L_;
    float* xdbl   = ws; ws += Kk * 38 * L_;
    float* delta  = ws; ws += Kk * DI_ * L_;
    float* BsT    = ws; ws += Kk * L_ * Nn;
    float* CsT    = ws; ws += Kk * L_ * Nn;
    float* Pw     = ws; ws += Kk * DI_ * NCH_ * Nn;
    float* Sw     = ws; ws += Kk * DI_ * NCH_ * Nn;
    float* HS     = ws; ws += Kk * DI_ * NCH_ * Nn;
    float* scan_y = ws; ws += Kk * DI_ * L_;
    float* x2     = ws; ws += C96 * L_;
    float* n2     = ws; ws += C96 * L_;
    float* hf     = ws; ws += 2 * HF_ * L_;
    float* gbuf   = ws; ws += HF_ * L_;

    dim3 b64x4(64, 4, 1);

    k_rmsln1<<<16, 256, 0, stream>>>(x, norm1_w, norm1_b, n1);
    k_inproj<<<dim3(64, 12), b64x4, 0, stream>>>(n1, in_proj_w, xzT);
    k_conv192<<<3072, 256, 0, stream>>>(xzT, conv2d_w, conv2d_b, xconv);
    k_build_xs<<<12288, 256, 0, stream>>>(xconv, xs);
    k_xdbl<<<dim3(64, 4, 5), 64, 0, stream>>>(xs, x_proj_w, xdbl);
    k_delta<<<12288, 256, 0, stream>>>(xdbl, dt_projs_w, dt_projs_b, delta);
    k_bct<<<1024, 256, 0, stream>>>(xdbl, BsT, CsT);
    k_scan1<<<1536, 256, 0, stream>>>(delta, xs, BsT, A_logs, Pw, Sw);
    k_scan2<<<48, 256, 0, stream>>>(Pw, Sw, HS);
    k_scan3<<<1536, 256, 0, stream>>>(delta, xs, BsT, CsT, A_logs, Ds, HS, scan_y);
    k_combine<<<4096, 192, 0, stream>>>(scan_y, out_norm_w, out_norm_b, xzT,
                                        out_proj_w, x, norm2_w, norm2_b, x2, n2);
    k_pin<<<dim3(64, 13), b64x4, 0, stream>>>(n2, pin_w, hf);
    k_ffnconv<<<4080, 256, 0, stream>>>(hf, dw_w, gbuf);
    k_pout<<<dim3(64, 3), b64x4, 0, stream>>>(gbuf, pout_w, x2, (float*)d_out);
}

// Round 2
// 336.163 us; speedup vs baseline: 1.2761x; 1.2761x over previous
//
#include <hip/hip_runtime.h>
#include <hip/hip_bf16.h>
#include <math.h>

#define L_    4096
#define C96   96
#define DI_   192
#define Nn    16
#define Rr    6
#define Kk    4
#define HW_   64
#define HF_   255
#define CH_   128
#define NCH_  32

__device__ __forceinline__ float sp_softplus(float s) {
    return fmaxf(s, 0.f) + log1pf(expf(-fabsf(s)));
}
__device__ __forceinline__ float sp_silu(float s) {
    return s / (1.f + expf(-s));
}

// K1: RMS-LN over C=96 channels (per spatial position). n1 layout (c, l).
__global__ void k_rmsln1(const float* __restrict__ x, const float* __restrict__ w,
                         const float* __restrict__ b, float* __restrict__ n1) {
    int l = blockIdx.x * blockDim.x + threadIdx.x;
    if (l >= L_) return;
    float ss = 0.f;
    for (int c = 0; c < C96; ++c) { float v = x[c * L_ + l]; ss += v * v; }
    float r = rsqrtf(ss * (1.f / C96) + 1e-6f);
    for (int c = 0; c < C96; ++c)
        n1[c * L_ + l] = x[c * L_ + l] * r * w[c] + b[c];
}

// K2: in_proj GEMM: xzT[o, l] = sum_c n1[c,l] * W[o,c].  O=384. 8-way o blocking.
__global__ void k_inproj(const float* __restrict__ n1, const float* __restrict__ W,
                         float* __restrict__ xzT) {
    int l = blockIdx.x * 64 + threadIdx.x;
    int o0 = (blockIdx.y * 4 + threadIdx.y) * 8;
    float acc[8] = {0.f, 0.f, 0.f, 0.f, 0.f, 0.f, 0.f, 0.f};
    for (int c = 0; c < C96; ++c) {
        float v = n1[c * L_ + l];
#pragma unroll
        for (int j = 0; j < 8; ++j) acc[j] += v * W[(o0 + j) * C96 + c];
    }
#pragma unroll
    for (int j = 0; j < 8; ++j) xzT[(o0 + j) * L_ + l] = acc[j];
}

// K3: depthwise 3x3 conv (SAME) + bias + SiLU on xc (192, 64, 64). Input = xzT rows 0..191.
__global__ void k_conv192(const float* __restrict__ xc, const float* __restrict__ w,
                          const float* __restrict__ b, float* __restrict__ out) {
    int idx = blockIdx.x * 256 + threadIdx.x;
    if (idx >= DI_ * L_) return;
    int c = idx / L_, l = idx % L_;
    int h = l >> 6, wc = l & 63;
    float s = b[c];
#pragma unroll
    for (int di = -1; di <= 1; ++di)
#pragma unroll
        for (int dj = -1; dj <= 1; ++dj) {
            int hh = h + di, ww = wc + dj;
            if (hh >= 0 && hh < HW_ && ww >= 0 && ww < HW_)
                s += xc[c * L_ + hh * HW_ + ww] * w[c * 9 + (di + 1) * 3 + (dj + 1)];
        }
    out[idx] = sp_silu(s);
}

// K4: materialize 4 direction views xs[(k*DI+d)*L + l]
__global__ void k_build_xs(const float* __restrict__ xconv, float* __restrict__ xs) {
    int idx = blockIdx.x * 256 + threadIdx.x;
    if (idx >= Kk * DI_ * L_) return;
    int l = idx % L_; int kd = idx / L_; int d = kd % DI_; int k = kd / DI_;
    int ll = (k & 2) ? (L_ - 1 - l) : l;
    int pos = (k & 1) ? ((ll & 63) * 64 + (ll >> 6)) : ll;
    xs[idx] = xconv[d * L_ + pos];
}

// K5v2: x_proj GEMM fused with B/C transpose.
// Block = 256 threads: one k, 64-wide l-tile, all 38 c outputs.
// Stage xs[192][64] (48KB LDS). Thread t: l = t&63, cgroup = t>>6.
// cg 0..2 -> 10 c each, cg 3 -> 8 c. W loads wave-uniform -> scalar.
// Writes: c<6 -> dts (k,r,l); 6..21 -> BsT (k,l,n); 22..37 -> CsT (k,l,n).
__global__ __launch_bounds__(256) void k_xdbl2(const float* __restrict__ xs,
        const float* __restrict__ Wxp, float* __restrict__ dts,
        float* __restrict__ BsT, float* __restrict__ CsT) {
    __shared__ float sx[DI_][64];
    int k = blockIdx.y;
    int l0 = blockIdx.x * 64;
    int t = threadIdx.x;
    const float* src = xs + (k * DI_) * L_ + l0;
    for (int i = t; i < DI_ * 64; i += 256) {
        int d = i >> 6, l = i & 63;
        sx[d][l] = src[d * L_ + l];
    }
    __syncthreads();
    int l = t & 63, cg = t >> 6;
    int c0 = cg * 10;
    int cnt = (cg == 3) ? 8 : 10;
    float acc[10] = {0.f, 0.f, 0.f, 0.f, 0.f, 0.f, 0.f, 0.f, 0.f, 0.f};
    const float* Wk = Wxp + k * 38 * DI_;
    for (int d = 0; d < DI_; ++d) {
        float v = sx[d][l];
#pragma unroll
        for (int j = 0; j < 10; ++j) {
            int cj = c0 + j; if (cj > 37) cj = 37;   // clamp keeps loads uniform
            acc[j] += v * Wk[cj * DI_ + d];
        }
    }
    int gl = l0 + l;
#pragma unroll
    for (int j = 0; j < 10; ++j) {
        if (j < cnt) {
            int c = c0 + j;
            float v = acc[j];
            if (c < Rr)       dts[(k * Rr + c) * L_ + gl] = v;
            else if (c < Rr + Nn) BsT[(k * L_ + gl) * Nn + (c - Rr)] = v;
            else              CsT[(k * L_ + gl) * Nn + (c - Rr - Nn)] = v;
        }
    }
}

// K6: delta[kd, l] = softplus(sum_r dts[k,r,l] * dtw[kd,r] + dtb[kd])
__global__ void k_delta(const float* __restrict__ dts, const float* __restrict__ dtw,
                        const float* __restrict__ dtb, float* __restrict__ delta) {
    int idx = blockIdx.x * 256 + threadIdx.x;
    if (idx >= Kk * DI_ * L_) return;
    int l = idx % L_; int kd = idx / L_; int k = kd / DI_;
    float s = dtb[kd];
#pragma unroll
    for (int r = 0; r < Rr; ++r)
        s += dts[(k * Rr + r) * L_ + l] * dtw[kd * Rr + r];
    delta[idx] = sp_softplus(s);
}

// K8: scan phase 1 — per-chunk (prod a, partial h) with h0 = 0.
__global__ void k_scan1(const float* __restrict__ delta, const float* __restrict__ xs,
                        const float* __restrict__ BsT, const float* __restrict__ A_logs,
                        float* __restrict__ P, float* __restrict__ S) {
    int g = blockIdx.x * 16 + (threadIdx.x >> 4);
    int n = threadIdx.x & 15;
    int chunk = g & 31; int kd = g >> 5; int k = kd / DI_;
    float A = -__expf(A_logs[kd * Nn + n]);
    float h = 0.f, p = 1.f;
    int base = kd * L_ + chunk * CH_;
    int base_b = (k * L_ + chunk * CH_) * Nn + n;
    for (int i = 0; i < CH_; ++i) {
        float dl = delta[base + i];
        float ul = xs[base + i];
        float bv = BsT[base_b + i * Nn];
        float e = __expf(dl * A);
        h = e * h + dl * ul * bv;
        p *= e;
    }
    int o = g * Nn + n;
    P[o] = p; S[o] = h;
}

// K9: scan phase 2 — exclusive prefix over 32 chunks per (kd).
__global__ void k_scan2(const float* __restrict__ P, const float* __restrict__ S,
                        float* __restrict__ HS) {
    int g = blockIdx.x * 16 + (threadIdx.x >> 4);
    int n = threadIdx.x & 15;
    if (g >= Kk * DI_) return;
    float h = 0.f;
    for (int c = 0; c < NCH_; ++c) {
        int o = (g * NCH_ + c) * Nn + n;
        HS[o] = h;
        h = P[o] * h + S[o];
    }
}

// K10: scan phase 3 — replay with correct h0, emit y = sum_n h*C + Dp*u.
__global__ void k_scan3(const float* __restrict__ delta, const float* __restrict__ xs,
                        const float* __restrict__ BsT, const float* __restrict__ CsT,
                        const float* __restrict__ A_logs, const float* __restrict__ Ds,
                        const float* __restrict__ HS, float* __restrict__ scan_y) {
    int g = blockIdx.x * 16 + (threadIdx.x >> 4);
    int n = threadIdx.x & 15;
    int chunk = g & 31; int kd = g >> 5; int k = kd / DI_;
    float A = -__expf(A_logs[kd * Nn + n]);
    float Dp = Ds[kd];
    float h = HS[(kd * NCH_ + chunk) * Nn + n];
    int base = kd * L_ + chunk * CH_;
    int base_bc = (k * L_ + chunk * CH_) * Nn + n;
    for (int i = 0; i < CH_; ++i) {
        float dl = delta[base + i];
        float ul = xs[base + i];
        float bv = BsT[base_bc + i * Nn];
        float cv = CsT[base_bc + i * Nn];
        float e = __expf(dl * A);
        h = e * h + dl * ul * bv;
        float psum = h * cv;
        psum += __shfl_xor(psum, 1, 64);
        psum += __shfl_xor(psum, 2, 64);
        psum += __shfl_xor(psum, 4, 64);
        psum += __shfl_xor(psum, 8, 64);
        if (n == 0) scan_y[base + i] = psum + Dp * ul;
    }
}

// K11: per-position: combine 4 directions + LayerNorm(DI) + silu(z) gate +
//      out_proj + residual + RMSNorm2. Block = 192 threads, 1 block per l.
__global__ __launch_bounds__(192) void k_combine(
        const float* __restrict__ scan_y, const float* __restrict__ onw,
        const float* __restrict__ onb, const float* __restrict__ xzT,
        const float* __restrict__ Wout, const float* __restrict__ x,
        const float* __restrict__ w2, const float* __restrict__ b2,
        float* __restrict__ x2, float* __restrict__ n2) {
    int l = blockIdx.x; int t = threadIdx.x;
    __shared__ float sh[192];
    __shared__ float shy[192];
    int h = l >> 6, wc = l & 63;
    int lT = (wc << 6) | h;
    float y = scan_y[(0 * DI_ + t) * L_ + l]
            + scan_y[(2 * DI_ + t) * L_ + (L_ - 1 - l)]
            + scan_y[(1 * DI_ + t) * L_ + lT]
            + scan_y[(3 * DI_ + t) * L_ + (L_ - 1 - lT)];
    sh[t] = y; __syncthreads();
    if (t < 64) {
        float v = sh[t] + sh[t + 64] + sh[t + 128];
        for (int m = 32; m; m >>= 1) v += __shfl_xor(v, m, 64);
        if (t == 0) sh[0] = v;
    }
    __syncthreads();
    float mu = sh[0] * (1.f / DI_);
    __syncthreads();
    float yc = y - mu;
    sh[t] = yc * yc; __syncthreads();
    if (t < 64) {
        float v = sh[t] + sh[t + 64] + sh[t + 128];
        for (int m = 32; m; m >>= 1) v += __shfl_xor(v, m, 64);
        if (t == 0) sh[0] = v;
    }
    __syncthreads();
    float var = sh[0] * (1.f / DI_);
    float zv = xzT[(DI_ + t) * L_ + l];
    float yn = yc * rsqrtf(var + 1e-5f) * onw[t] + onb[t];
    yn *= sp_silu(zv);
    shy[t] = yn;
    __syncthreads();
    float x2v = 0.f;
    if (t < C96) {
        float acc = 0.f;
        for (int d = 0; d < DI_; ++d) acc += shy[d] * Wout[t * DI_ + d];
        x2v = x[t * L_ + l] + acc;
    }
    __syncthreads();
    sh[t] = (t < C96) ? x2v * x2v : 0.f;
    __syncthreads();
    if (t < 32) {
        float v = sh[t] + sh[t + 32] + sh[t + 64];
        for (int m = 16; m; m >>= 1) v += __shfl_xor(v, m, 64);
        if (t == 0) sh[0] = v;
    }
    __syncthreads();
    float r2 = rsqrtf(sh[0] * (1.f / C96) + 1e-6f);
    if (t < C96) {
        x2[t * L_ + l] = x2v;
        n2[t * L_ + l] = x2v * r2 * w2[t] + b2[t];
    }
}

// K12: EDFFN pin GEMM: hf[o, l] = sum_c n2[c,l] * W[o,c].  O=510, 10-way blocking.
__global__ void k_pin(const float* __restrict__ n2, const float* __restrict__ W,
                      float* __restrict__ hf) {
    int l = blockIdx.x * 64 + threadIdx.x;
    int g = blockIdx.y * 4 + threadIdx.y;
    if (g >= 51) return;
    int o0 = g * 10;
    float acc[10] = {0.f, 0.f, 0.f, 0.f, 0.f, 0.f, 0.f, 0.f, 0.f, 0.f};
    for (int c = 0; c < C96; ++c) {
        float v = n2[c * L_ + l];
#pragma unroll
        for (int j = 0; j < 10; ++j) acc[j] += v * W[(o0 + j) * C96 + c];
    }
#pragma unroll
    for (int j = 0; j < 10; ++j) hf[(o0 + j) * L_ + l] = acc[j];
}

// K13: depthwise 3x3 (no bias) on 510 channels + GELU(h1)*h2 gate. g (255, l).
__global__ void k_ffnconv(const float* __restrict__ hf, const float* __restrict__ w,
                          float* __restrict__ g) {
    int idx = blockIdx.x * 256 + threadIdx.x;
    if (idx >= HF_ * L_) return;
    int c = idx / L_, l = idx % L_;
    int h = l >> 6, wc = l & 63;
    float s1 = 0.f, s2 = 0.f;
#pragma unroll
    for (int di = -1; di <= 1; ++di)
#pragma unroll
        for (int dj = -1; dj <= 1; ++dj) {
            int hh = h + di, ww = wc + dj;
            if (hh >= 0 && hh < HW_ && ww >= 0 && ww < HW_) {
                int p = hh * HW_ + ww;
                int widx = (di + 1) * 3 + (dj + 1);
                s1 += hf[c * L_ + p] * w[c * 9 + widx];
                s2 += hf[(c + HF_) * L_ + p] * w[(c + HF_) * 9 + widx];
            }
        }
    float ge = 0.5f * s1 * (1.f + erff(s1 * 0.70710678118654752f));
    g[idx] = ge * s2;
}

// K14: pout GEMM + final residual: out[c,l] = x2[c,l] + sum_i g[i,l]*W[c,i].
__global__ void k_pout(const float* __restrict__ g, const float* __restrict__ W,
                       const float* __restrict__ x2, float* __restrict__ out) {
    int l = blockIdx.x * 64 + threadIdx.x;
    int c0 = (blockIdx.y * 4 + threadIdx.y) * 8;
    float acc[8] = {0.f, 0.f, 0.f, 0.f, 0.f, 0.f, 0.f, 0.f};
    for (int i = 0; i < HF_; ++i) {
        float v = g[i * L_ + l];
#pragma unroll
        for (int j = 0; j < 8; ++j) acc[j] += v * W[(c0 + j) * HF_ + i];
    }
#pragma unroll
    for (int j = 0; j < 8; ++j)
        out[(c0 + j) * L_ + l] = x2[(c0 + j) * L_ + l] + acc[j];
}

extern "C" void kernel_launch(void* const* d_in, const int* in_sizes, int n_in,
                              void* d_out, int out_size, void* d_ws, size_t ws_size,
                              hipStream_t stream) {
    const float* x         = (const float*)d_in[0];
    const float* norm1_w   = (const float*)d_in[1];
    const float* norm1_b   = (const float*)d_in[2];
    const float* in_proj_w = (const float*)d_in[3];
    const float* conv2d_w  = (const float*)d_in[4];
    const float* conv2d_b  = (const float*)d_in[5];
    const float* x_proj_w  = (const float*)d_in[6];
    const float* dt_projs_w= (const float*)d_in[7];
    const float* dt_projs_b= (const float*)d_in[8];
    const float* A_logs    = (const float*)d_in[9];
    const float* Ds        = (const float*)d_in[10];
    const float* out_norm_w= (const float*)d_in[11];
    const float* out_norm_b= (const float*)d_in[12];
    const float* out_proj_w= (const float*)d_in[13];
    const float* norm2_w   = (const float*)d_in[14];
    const float* norm2_b   = (const float*)d_in[15];
    const float* pin_w     = (const float*)d_in[16];
    const float* dw_w      = (const float*)d_in[17];
    const float* pout_w    = (const float*)d_in[18];

    float* ws = (float*)d_ws;
    float* n1     = ws; ws += C96 * L_;
    float* xzT    = ws; ws += 2 * DI_ * L_;
    float* xconv  = ws; ws += DI_ * L_;
    float* xs     = ws; ws += Kk * DI_ * L_;
    float* dtsb   = ws; ws += Kk * Rr * L_;
    float* delta  = ws; ws += Kk * DI_ * L_;
    float* BsT    = ws; ws += Kk * L_ * Nn;
    float* CsT    = ws; ws += Kk * L_ * Nn;
    float* Pw     = ws; ws += Kk * DI_ * NCH_ * Nn;
    float* Sw     = ws; ws += Kk * DI_ * NCH_ * Nn;
    float* HS     = ws; ws += Kk * DI_ * NCH_ * Nn;
    float* scan_y = ws; ws += Kk * DI_ * L_;
    float* x2     = ws; ws += C96 * L_;
    float* n2     = ws; ws += C96 * L_;
    float* hf     = ws; ws += 2 * HF_ * L_;
    float* gbuf   = ws; ws += HF_ * L_;

    dim3 b64x4(64, 4, 1);

    k_rmsln1<<<16, 256, 0, stream>>>(x, norm1_w, norm1_b, n1);
    k_inproj<<<dim3(64, 12), b64x4, 0, stream>>>(n1, in_proj_w, xzT);
    k_conv192<<<3072, 256, 0, stream>>>(xzT, conv2d_w, conv2d_b, xconv);
    k_build_xs<<<12288, 256, 0, stream>>>(xconv, xs);
    k_xdbl2<<<dim3(64, 4), 256, 0, stream>>>(xs, x_proj_w, dtsb, BsT, CsT);
    k_delta<<<12288, 256, 0, stream>>>(dtsb, dt_projs_w, dt_projs_b, delta);
    k_scan1<<<1536, 256, 0, stream>>>(delta, xs, BsT, A_logs, Pw, Sw);
    k_scan2<<<48, 256, 0, stream>>>(Pw, Sw, HS);
    k_scan3<<<1536, 256, 0, stream>>>(delta, xs, BsT, CsT, A_logs, Ds, HS, scan_y);
    k_combine<<<4096, 192, 0, stream>>>(scan_y, out_norm_w, out_norm_b, xzT,
                                        out_proj_w, x, norm2_w, norm2_b, x2, n2);
    k_pin<<<dim3(64, 13), b64x4, 0, stream>>>(n2, pin_w, hf);
    k_ffnconv<<<4080, 256, 0, stream>>>(hf, dw_w, gbuf);
    k_pout<<<dim3(64, 3), b64x4, 0, stream>>>(gbuf, pout_w, x2, (float*)d_out);
}